// Round 13
// baseline (355.669 us; speedup 1.0000x reference)
//
#include <hip/hip_runtime.h>

#define IN_F   8192
#define OUT_F  14336
#define M_TOK  64
#define KPI    4096              // packed int32 per weight row
#define BN     128               // n per block (4 waves x 32)
#define NBLK   (OUT_F / BN)      // 112
#define KSPLIT 16
#define KCHUNK (IN_F / KSPLIT)   // 512 k per block
#define BK     64                // k per staging step
#define NSTEP  (KCHUNK / BK)     // 8
#define XB_BLOCKS ((M_TOK * IN_F) / 4 / 256)   // 512
#define OI_BLOCKS ((M_TOK * OUT_F) / 4 / 256)  // 896

typedef __attribute__((ext_vector_type(8)))  short bf16x8;   // 8 bf16 (4 VGPRs)
typedef __attribute__((ext_vector_type(16))) float f32x16;   // 32x32 MFMA C/D frag

__device__ __forceinline__ unsigned short f2bf_rne(float f) {
    unsigned u = __builtin_bit_cast(unsigned, f);
    u += 0x7FFFu + ((u >> 16) & 1u);
    return (unsigned short)(u >> 16);
}

// Combined setup: blocks [0,512) convert x fp32 -> bf16; blocks [512,1408)
// initialize out[m][n] = bias[n] (gemm atomically accumulates into out).
__global__ __launch_bounds__(256) void qlin_setup(const float* __restrict__ x,
                                                  const float* __restrict__ bias,
                                                  unsigned short* __restrict__ xb,
                                                  float* __restrict__ out) {
    const int b   = blockIdx.x;
    const int tid = threadIdx.x;
    if (b < XB_BLOCKS) {
        int gid = b * 256 + tid;                       // 131072 float4
        float4 v = reinterpret_cast<const float4*>(x)[gid];
        ushort4 o;
        o.x = f2bf_rne(v.x);
        o.y = f2bf_rne(v.y);
        o.z = f2bf_rne(v.z);
        o.w = f2bf_rne(v.w);
        reinterpret_cast<ushort4*>(xb)[gid] = o;
    } else {
        int idx = (b - XB_BLOCKS) * 256 + tid;         // 0..229375 float4
        int nq  = idx % (OUT_F / 4);                   // compiler magic-div
        reinterpret_cast<float4*>(out)[idx] =
            reinterpret_cast<const float4*>(bias)[nq];
    }
}

// One packed int32 (byte: lo nibble = even k, hi nibble = odd k) -> two bf16
// bit-patterns in one dword. Ints in [-8,7] are exact in bf16.
__device__ __forceinline__ int unpack2_bf16(int v) {
    int q0 = ((int)((unsigned)v << 28)) >> 28;
    int q1 = ((int)((unsigned)v << 24)) >> 28;
    unsigned u0 = __builtin_bit_cast(unsigned, (float)q0);
    unsigned u1 = __builtin_bit_cast(unsigned, (float)q1);
    return (int)((u0 >> 16) | (u1 & 0xFFFF0000u));
}

__device__ __forceinline__ bf16x8 unpack_b(int4 wv) {
    int4 pk;
    pk.x = unpack2_bf16(wv.x);
    pk.y = unpack2_bf16(wv.y);
    pk.z = unpack2_bf16(wv.z);
    pk.w = unpack2_bf16(wv.w);
    return __builtin_bit_cast(bf16x8, pk);
}

// async 16-B global -> LDS (LDS dest = wave-uniform base + lane*16, fixed by HW).
__device__ __forceinline__ void gload_lds16(const void* g, void* l) {
    __builtin_amdgcn_global_load_lds(
        (const __attribute__((address_space(1))) unsigned int*)g,
        (__attribute__((address_space(3))) unsigned int*)l,
        16, 0, 0);
}

// Round-11 change (one change-set): 3-buffer, ONE-barrier-per-step, stage-early
// K-loop. Rationale: the 2-buffer schedule paid 2 barriers + wait per step
// (16 barriers/block) and staged only after COMPUTE, so every tile had <1
// compute-phase of load cover and 4-wave convoys re-formed twice per step.
// With 3 buffers, the overwrite target at iter t (buf[(t+2)%3]) was last read
// at iter t-1, so the single barrier at the top of iter t suffices:
//   write@t vs next-read@t+2: two barriers between; vs prev-read@t-1: one.
// Per-wave ds_reads are all consumed by MFMAs before the wave reaches the
// next barrier (lgkm FIFO => complete), so no second barrier is needed.
// Counted vmcnt(6) kept (2 tiles x 6 ops in flight; never 0 in-loop); loads
// now get ~2 full iterations of cover. Cost: LDS 48->72 KB => 2 blocks/CU.
// wait-THEN-barrier order is load-bearing: a wave's vmcnt only covers its own
// gload_lds ops; the barrier makes every wave's tile-t loads visible to all.
__global__ __launch_bounds__(256) void qlin_gemm(const unsigned short* __restrict__ xb,
                                                 const int* __restrict__ wp,
                                                 const float* __restrict__ scales,
                                                 float* __restrict__ out) {
    __shared__ int            wlds[3][BN * (BK / 2)];   // 3 x 16 KB
    __shared__ unsigned short xlds[3][M_TOK * BK];      // 3 x  8 KB  (72 KB total)

    const int tid  = threadIdx.x;
    const int wave = tid >> 6;
    const int lane = tid & 63;
    const int tp   = lane & 31;   // 32x32 frag: n (B) / m (A) / col (C)
    const int qp   = lane >> 5;   // 32x32 frag: k-half ; C/D row offset 4*qp

    const int nblk = blockIdx.x % NBLK;
    const int kblk = blockIdx.x / NBLK;
    const int n0   = nblk * BN;
    const int kb   = kblk * KCHUNK;        // k base (elements)

    f32x16 acc0 = {0.f,0.f,0.f,0.f,0.f,0.f,0.f,0.f,0.f,0.f,0.f,0.f,0.f,0.f,0.f,0.f};
    f32x16 acc1 = acc0;

    // ---- stage tile t into buffer b: 16 instrs w + 8 instrs x per block ----
#define STAGE(b, t) do {                                                           \
    _Pragma("unroll")                                                              \
    for (int j = 0; j < 4; ++j) {                                                  \
        int li = (wave * 4 + j) * 64 + lane;       /* slot 0..1023 */              \
        int r  = li >> 3;                          /* weight row 0..127 */         \
        int cg = (li & 7) ^ (r & 7);               /* global chunk (swizzled) */   \
        const int* gp = wp + (size_t)(n0 + r) * KPI + (kb >> 1) + (t) * (BK / 2) + cg * 4; \
        gload_lds16(gp, (char*)&wlds[b][0] + (size_t)li * 16);                     \
    }                                                                              \
    _Pragma("unroll")                                                              \
    for (int j = 0; j < 2; ++j) {                                                  \
        int li = (wave * 2 + j) * 64 + lane;       /* slot 0..511 */               \
        int r  = li >> 3;                          /* m row 0..63 */               \
        int cg = (li & 7) ^ (r & 7);                                               \
        const unsigned short* gp = xb + (size_t)r * IN_F + kb + (t) * BK + cg * 8; \
        gload_lds16(gp, (char*)&xlds[b][0] + (size_t)li * 16);                     \
    }                                                                              \
} while (0)

#define COMPUTE(b) do {                                                            \
    _Pragma("unroll")                                                              \
    for (int kf = 0; kf < 4; ++kf) {                                               \
        const int c = kf * 2 + qp;                 /* 16-B chunk within row */     \
        const int R = wave * 32 + tp;                                              \
        int4 wv = *reinterpret_cast<const int4*>(                                  \
            (const char*)&wlds[b][0] + (size_t)(R * 8 + (c ^ (R & 7))) * 16);      \
        bf16x8 bb = unpack_b(wv);                                                  \
        bf16x8 a0 = *reinterpret_cast<const bf16x8*>(                              \
            (const char*)&xlds[b][0] + (size_t)(tp * 8 + (c ^ (tp & 7))) * 16);    \
        bf16x8 a1 = *reinterpret_cast<const bf16x8*>(                              \
            (const char*)&xlds[b][0] + (size_t)((32 + tp) * 8 + (c ^ (tp & 7))) * 16); \
        acc0 = __builtin_amdgcn_mfma_f32_32x32x16_bf16(a0, bb, acc0, 0, 0, 0);     \
        acc1 = __builtin_amdgcn_mfma_f32_32x32x16_bf16(a1, bb, acc1, 0, 0, 0);     \
    }                                                                              \
} while (0)

    // prologue: 2-deep prefetch (12 vmem ops/wave in flight)
    STAGE(0, 0);
    STAGE(1, 1);

#pragma unroll
    for (int t = 0; t < NSTEP - 1; ++t) {
        // tile t landed when only tile t+1's 6 ops remain outstanding (FIFO)
        asm volatile("s_waitcnt vmcnt(6)" ::: "memory");
        __builtin_amdgcn_sched_barrier(0);
        __builtin_amdgcn_s_barrier();          // all waves' tile-t loads visible
        __builtin_amdgcn_sched_barrier(0);
        if (t + 2 < NSTEP) STAGE((t + 2) % 3, t + 2);   // issue-early: ~2 iters of cover
        COMPUTE(t % 3);
    }
    // peeled final tile: its 6 ops are the newest -> full drain
    asm volatile("s_waitcnt vmcnt(0)" ::: "memory");
    __builtin_amdgcn_sched_barrier(0);
    __builtin_amdgcn_s_barrier();
    __builtin_amdgcn_sched_barrier(0);
    COMPUTE((NSTEP - 1) % 3);

    // ---- epilogue: C/D layout col=tp, row=(reg&3)+8*(reg>>2)+4*qp ----
    // out was pre-filled with bias; accumulate scale*acc with HW f32 atomics
    // (device-scope, order-independent across the 16 k-splits).
    const int   n  = n0 + wave * 32 + tp;
    const float sc = scales[n];
#pragma unroll
    for (int reg = 0; reg < 16; ++reg) {
        int m = (reg & 3) + 8 * (reg >> 2) + 4 * qp;
        unsafeAtomicAdd(out + (size_t)m        * OUT_F + n, acc0[reg] * sc);
        unsafeAtomicAdd(out + (size_t)(32 + m) * OUT_F + n, acc1[reg] * sc);
    }
#undef STAGE
#undef COMPUTE
}

extern "C" void kernel_launch(void* const* d_in, const int* in_sizes, int n_in,
                              void* d_out, int out_size, void* d_ws, size_t ws_size,
                              hipStream_t stream) {
    const float* x    = (const float*)d_in[0];
    const int*   wp   = (const int*)d_in[1];
    const float* sc   = (const float*)d_in[2];
    const float* bias = (const float*)d_in[3];
    float* out = (float*)d_out;

    unsigned short* xb = (unsigned short*)d_ws;   // 1 MB (only ws use)

    qlin_setup<<<XB_BLOCKS + OI_BLOCKS, 256, 0, stream>>>(x, bias, xb, out);
    qlin_gemm<<<NBLK * KSPLIT, 256, 0, stream>>>(xb, wp, sc, out);
}

// Round 14
// 340.239 us; speedup vs baseline: 1.0454x; 1.0454x over previous
//
#include <hip/hip_runtime.h>

#define IN_F   8192
#define OUT_F  14336
#define M_TOK  64
#define KPI    4096              // packed int32 per weight row
#define BN     64                // n per block (4 waves: 2x2 32x32 quadrants)
#define NBLK   (OUT_F / BN)      // 224
#define KSPLIT 16
#define KCHUNK (IN_F / KSPLIT)   // 512 k per block
#define BK     64                // k per staging step
#define NSTEP  (KCHUNK / BK)     // 8
#define XB_BLOCKS ((M_TOK * IN_F) / 4 / 256)   // 512
#define OI_BLOCKS ((M_TOK * OUT_F) / 4 / 256)  // 896

typedef __attribute__((ext_vector_type(8)))  short bf16x8;   // 8 bf16 (4 VGPRs)
typedef __attribute__((ext_vector_type(16))) float f32x16;   // 32x32 MFMA C/D frag

__device__ __forceinline__ unsigned short f2bf_rne(float f) {
    unsigned u = __builtin_bit_cast(unsigned, f);
    u += 0x7FFFu + ((u >> 16) & 1u);
    return (unsigned short)(u >> 16);
}

// Combined setup: blocks [0,512) convert x fp32 -> bf16; blocks [512,1408)
// initialize out[m][n] = bias[n] (gemm atomically accumulates into out).
__global__ __launch_bounds__(256) void qlin_setup(const float* __restrict__ x,
                                                  const float* __restrict__ bias,
                                                  unsigned short* __restrict__ xb,
                                                  float* __restrict__ out) {
    const int b   = blockIdx.x;
    const int tid = threadIdx.x;
    if (b < XB_BLOCKS) {
        int gid = b * 256 + tid;                       // 131072 float4
        float4 v = reinterpret_cast<const float4*>(x)[gid];
        ushort4 o;
        o.x = f2bf_rne(v.x);
        o.y = f2bf_rne(v.y);
        o.z = f2bf_rne(v.z);
        o.w = f2bf_rne(v.w);
        reinterpret_cast<ushort4*>(xb)[gid] = o;
    } else {
        int idx = (b - XB_BLOCKS) * 256 + tid;         // 0..229375 float4
        int nq  = idx % (OUT_F / 4);                   // compiler magic-div
        reinterpret_cast<float4*>(out)[idx] =
            reinterpret_cast<const float4*>(bias)[nq];
    }
}

// One packed int32 (byte: lo nibble = even k, hi nibble = odd k) -> two bf16
// bit-patterns in one dword. Ints in [-8,7] are exact in bf16.
__device__ __forceinline__ int unpack2_bf16(int v) {
    int q0 = ((int)((unsigned)v << 28)) >> 28;
    int q1 = ((int)((unsigned)v << 24)) >> 28;
    unsigned u0 = __builtin_bit_cast(unsigned, (float)q0);
    unsigned u1 = __builtin_bit_cast(unsigned, (float)q1);
    return (int)((u0 >> 16) | (u1 & 0xFFFF0000u));
}

__device__ __forceinline__ bf16x8 unpack_b(int4 wv) {
    int4 pk;
    pk.x = unpack2_bf16(wv.x);
    pk.y = unpack2_bf16(wv.y);
    pk.z = unpack2_bf16(wv.z);
    pk.w = unpack2_bf16(wv.w);
    return __builtin_bit_cast(bf16x8, pk);
}

// async 16-B global -> LDS (LDS dest = wave-uniform base + lane*16, fixed by HW).
__device__ __forceinline__ void gload_lds16(const void* g, void* l) {
    __builtin_amdgcn_global_load_lds(
        (const __attribute__((address_space(1))) unsigned int*)g,
        (__attribute__((address_space(3))) unsigned int*)l,
        16, 0, 0);
}

// Round-14: revert to the measured-good R10 schedule (2-buffer, 2 barriers
// per step, counted vmcnt, STAGE-after-COMPUTE) and push OCCUPANCY, which
// R13 identified as the binding resource:
//   measured gradient: 2 blk/CU (72KB) = 149 us; 3 blk/CU (48KB) <= 137 us;
//   all pipes idle (Mfma 3.8 / VALU 8.5 / HBM 15%) => latency/queue-bound,
//   more independent block pipelines is what helps, not fewer barriers.
// Change: BN 128->64, one 32x32 output per wave (wave=(mh,nh) quadrant).
//   LDS 48->32 KB => 5 blocks/CU (20 waves/CU); acc 32->16 VGPR => compiler
//   ~60-70 VGPR (below the 128 cliff, near the 64 cliff). Proven c^(r&7)
//   swizzle and fragment math unchanged; per-wave staging 6->4 instrs =>
//   in-loop wait vmcnt(4). Weight traffic identical (each (row,kchunk)
//   staged once); extra x-tile re-reads are L2-resident (~3 us chip-wide).
__global__ __launch_bounds__(256) void qlin_gemm(const unsigned short* __restrict__ xb,
                                                 const int* __restrict__ wp,
                                                 const float* __restrict__ scales,
                                                 float* __restrict__ out) {
    __shared__ int            wlds[2][BN * (BK / 2)];   // 2 x 8 KB
    __shared__ unsigned short xlds[2][M_TOK * BK];      // 2 x 8 KB  (32 KB -> 5 blocks/CU)

    const int tid  = threadIdx.x;
    const int wave = tid >> 6;
    const int lane = tid & 63;
    const int tp   = lane & 31;   // 32x32 frag: n (B) / m (A) / col (C)
    const int qp   = lane >> 5;   // 32x32 frag: k-half ; C/D row offset 4*qp
    const int nh   = wave & 1;    // n-half of this wave's 32x32 quadrant
    const int mh   = wave >> 1;   // m-half

    const int nblk = blockIdx.x % NBLK;
    const int kblk = blockIdx.x / NBLK;
    const int n0   = nblk * BN;
    const int kb   = kblk * KCHUNK;        // k base (elements)

    f32x16 acc = {0.f,0.f,0.f,0.f,0.f,0.f,0.f,0.f,0.f,0.f,0.f,0.f,0.f,0.f,0.f,0.f};

    // ---- stage tile t into buffer b: 8 instrs w + 8 instrs x per block ----
#define STAGE(b, t) do {                                                           \
    _Pragma("unroll")                                                              \
    for (int j = 0; j < 2; ++j) {                                                  \
        int li = (wave * 2 + j) * 64 + lane;       /* slot 0..511 */               \
        int r  = li >> 3;                          /* weight row 0..63 */          \
        int cg = (li & 7) ^ (r & 7);               /* global chunk (swizzled) */   \
        const int* gp = wp + (size_t)(n0 + r) * KPI + (kb >> 1) + (t) * (BK / 2) + cg * 4; \
        gload_lds16(gp, (char*)&wlds[b][0] + (size_t)li * 16);                     \
    }                                                                              \
    _Pragma("unroll")                                                              \
    for (int j = 0; j < 2; ++j) {                                                  \
        int li = (wave * 2 + j) * 64 + lane;       /* slot 0..511 */               \
        int r  = li >> 3;                          /* m row 0..63 */               \
        int cg = (li & 7) ^ (r & 7);                                               \
        const unsigned short* gp = xb + (size_t)r * IN_F + kb + (t) * BK + cg * 8; \
        gload_lds16(gp, (char*)&xlds[b][0] + (size_t)li * 16);                     \
    }                                                                              \
} while (0)

#define COMPUTE(b) do {                                                            \
    _Pragma("unroll")                                                              \
    for (int kf = 0; kf < 4; ++kf) {                                               \
        const int c  = kf * 2 + qp;                /* 16-B chunk within row */     \
        const int Rn = nh * 32 + tp;               /* weight row of this wave */   \
        const int Rm = mh * 32 + tp;               /* x row of this wave */        \
        int4 wv = *reinterpret_cast<const int4*>(                                  \
            (const char*)&wlds[b][0] + (size_t)(Rn * 8 + (c ^ (Rn & 7))) * 16);    \
        bf16x8 bb = unpack_b(wv);                                                  \
        bf16x8 aa = *reinterpret_cast<const bf16x8*>(                              \
            (const char*)&xlds[b][0] + (size_t)(Rm * 8 + (c ^ (Rm & 7))) * 16);    \
        acc = __builtin_amdgcn_mfma_f32_32x32x16_bf16(aa, bb, acc, 0, 0, 0);       \
    }                                                                              \
} while (0)

    // prologue: 2-deep prefetch (8 vmem ops/wave in flight)
    STAGE(0, 0);
    STAGE(1, 1);

    for (int t = 0; t < NSTEP - 1; ++t) {
        const int cur = t & 1;
        // tile t complete when only tile t+1's 4 ops remain outstanding
        asm volatile("s_waitcnt vmcnt(4)" ::: "memory");
        __builtin_amdgcn_sched_barrier(0);
        __builtin_amdgcn_s_barrier();
        __builtin_amdgcn_sched_barrier(0);
        COMPUTE(cur);
        // every ds_read above is consumed by an MFMA before this barrier,
        // so after it buf[cur] is dead for all waves -> safe to overwrite.
        __builtin_amdgcn_sched_barrier(0);
        __builtin_amdgcn_s_barrier();
        __builtin_amdgcn_sched_barrier(0);
        if (t + 2 < NSTEP) STAGE(cur, t + 2);
    }
    // peeled final tile: its 4 ops are the newest -> full drain
    asm volatile("s_waitcnt vmcnt(0)" ::: "memory");
    __builtin_amdgcn_sched_barrier(0);
    __builtin_amdgcn_s_barrier();
    __builtin_amdgcn_sched_barrier(0);
    COMPUTE((NSTEP - 1) & 1);

    // ---- epilogue: C/D layout col=tp, row=(reg&3)+8*(reg>>2)+4*qp ----
    // out was pre-filled with bias; accumulate scale*acc with HW f32 atomics
    // (device-scope, order-independent across the 16 k-splits).
    const int   n  = n0 + nh * 32 + tp;
    const float sc = scales[n];
#pragma unroll
    for (int reg = 0; reg < 16; ++reg) {
        int m = mh * 32 + (reg & 3) + 8 * (reg >> 2) + 4 * qp;
        unsafeAtomicAdd(out + (size_t)m * OUT_F + n, acc[reg] * sc);
    }
#undef STAGE
#undef COMPUTE
}

extern "C" void kernel_launch(void* const* d_in, const int* in_sizes, int n_in,
                              void* d_out, int out_size, void* d_ws, size_t ws_size,
                              hipStream_t stream) {
    const float* x    = (const float*)d_in[0];
    const int*   wp   = (const int*)d_in[1];
    const float* sc   = (const float*)d_in[2];
    const float* bias = (const float*)d_in[3];
    float* out = (float*)d_out;

    unsigned short* xb = (unsigned short*)d_ws;   // 1 MB (only ws use)

    qlin_setup<<<XB_BLOCKS + OI_BLOCKS, 256, 0, stream>>>(x, bias, xb, out);
    qlin_gemm<<<NBLK * KSPLIT, 256, 0, stream>>>(xb, wp, sc, out);
}